// Round 16
// baseline (80.375 us; speedup 1.0000x reference)
//
#include <hip/hip_runtime.h>
#include <hip/hip_fp16.h>

typedef _Float16 f16x8 __attribute__((ext_vector_type(8)));
typedef _Float16 f16x4 __attribute__((ext_vector_type(4)));
typedef _Float16 f16x2 __attribute__((ext_vector_type(2)));
typedef float    f32x4 __attribute__((ext_vector_type(4)));

#define BM 64     // 64-row block tile -> 76.8 KB LDS -> 2 blocks/CU, 4 waves/SIMD

// layer geometry (h=0 => only first IN rows of each weight matter; the
// padded K range includes a bias row at k==IN carrying 1.0 in activations)
#define IN0 74
#define H0  269
#define H1  179
#define H2  64
#define KS0 3     // ceil((IN0+1)/32)
#define KS1 9     // ceil((H0+1)/32)
#define KS2 6     // ceil((H1+1)/32)
#define NP0 272
#define NP1 192
#define NP2 64
#define PX  104   // LDS row pitches (halfs)
#define PH0 296
#define PH1 200

// SWAPPED operands: weights as the A-matrix, activations as B.
// C/D layout: col(lane&15)=batch row, row(lg*4+q)=feature -> each lane's 4
// outputs are 4 CONSECUTIVE features of one batch row.
#define MFMA16(a, b, c) __builtin_amdgcn_mfma_f32_16x16x32_f16(a, b, c, 0, 0, 0)

// THREE matrices per layer: m0 = 2*log2e*mask*Wf1 (+bias row), m1 = same for
// Wf2, m2 = log2e*(Wtb-Wta) (+bias). log2e folded at pack time so the
// epilogue uses raw exp2: tanh(f) = 1-2r, r = 1/(1+exp2(acc));
// ti = sigmoid(tb-ta) = 1/(1+exp2(-acc2)).
__device__ __forceinline__ float rform2(float y) {
  return __builtin_amdgcn_rcpf(1.f + exp2f(y));
}

// One PART of a CfC layer: NU work-units starting at tile T0, each unit
// u -> (tile T0 + u/G, row-group u%G of S*16 rows). 8 waves stride the
// units. Layers are split into a large-S part + small-S remainder so
// per-wave cost is uniform (r12's ceil() tails were ~31% idle).
// Per unit ONE K-sweep, 3 matrices accumulating (acc[3][S] AGPRs), rolling
// 1-ahead B window in a FORCIBLY ROLLED (#pragma unroll 1) ks loop, A-reads
// just-in-time in the unrolled s-loop (r12 structure, the proven best).
template<int KS, int HID, int IPITCH, int OPITCH, bool LAST, int S, int G>
__device__ __forceinline__ void layer_part(
    const _Float16* in_lds, _Float16* out_lds, float* out_g,
    const _Float16* __restrict__ wt, int lane, int wid, int T0, int NU)
{
  const int l15 = lane & 15;
  const int lg  = lane >> 4;
  #pragma unroll 1
  for (int u = wid; u < NU; u += 8) {
    const int t     = T0 + u / G;
    const int mbase = (u % G) * (S * 16);
    const _Float16* a_base = in_lds + (mbase + l15) * IPITCH + lg * 8;
    const _Float16* wtt = wt + (size_t)(t * KS * 3) * 512 + lane * 8;

    f32x4 acc[3][S] = {};
    f16x8 b0 = *(const f16x8*)(wtt);
    f16x8 b1 = *(const f16x8*)(wtt + 512);
    f16x8 b2 = *(const f16x8*)(wtt + 1024);
    #pragma unroll 1
    for (int ks = 0; ks < KS - 1; ++ks) {
      const _Float16* wn = wtt + (size_t)(ks + 1) * 1536;
      f16x8 n0 = *(const f16x8*)(wn);
      f16x8 n1 = *(const f16x8*)(wn + 512);
      f16x8 n2 = *(const f16x8*)(wn + 1024);
      #pragma unroll
      for (int s = 0; s < S; ++s) {
        f16x8 a = *(const f16x8*)(a_base + s * 16 * IPITCH + ks * 32);
        acc[0][s] = MFMA16(b0, a, acc[0][s]);
        acc[1][s] = MFMA16(b1, a, acc[1][s]);
        acc[2][s] = MFMA16(b2, a, acc[2][s]);
      }
      b0 = n0; b1 = n1; b2 = n2;
    }
    #pragma unroll
    for (int s = 0; s < S; ++s) {
      f16x8 a = *(const f16x8*)(a_base + s * 16 * IPITCH + (KS - 1) * 32);
      acc[0][s] = MFMA16(b0, a, acc[0][s]);
      acc[1][s] = MFMA16(b1, a, acc[1][s]);
      acc[2][s] = MFMA16(b2, a, acc[2][s]);
    }

    // epilogue: per s, this lane owns batch row m and 4 consecutive features
    const int nb = t * 16 + lg * 4;
    #pragma unroll
    for (int s = 0; s < S; ++s) {
      const int m = mbase + s * 16 + l15;
      float o[4];
      #pragma unroll
      for (int q = 0; q < 4; ++q) {
        float r1 = rform2(acc[0][s][q]);        // acc0 = 2*log2e*f1
        float r2 = rform2(acc[1][s][q]);        // acc1 = 2*log2e*f2
        float ti = rform2(-acc[2][s][q]);       // sigmoid(tb-ta)
        o[q] = 1.f - 2.f * (r1 - ti * (r1 - r2));
      }
      if (LAST) {
        float4 v = make_float4(o[0], o[1], o[2], o[3]);
        *(float4*)(out_g + m * 64 + nb) = v;       // NP2==H2, no guard
      } else if (nb + 4 <= HID) {
        f16x4 h = {(_Float16)o[0], (_Float16)o[1], (_Float16)o[2], (_Float16)o[3]};
        *(f16x4*)(out_lds + m * OPITCH + nb) = h;  // one b64 write
      } else {
        #pragma unroll
        for (int q = 0; q < 4; ++q)
          if (nb + q < HID) out_lds[m * OPITCH + nb + q] = (_Float16)o[q];
      }
    }
  }
}

__global__ __launch_bounds__(512, 4) void cfc_fused(
    const float* __restrict__ x,
    const _Float16* __restrict__ wt0, const _Float16* __restrict__ wt1,
    const _Float16* __restrict__ wt2,
    float* __restrict__ out)
{
  __shared__ __align__(16) _Float16 xs [BM * PX];   // 13312 B
  __shared__ __align__(16) _Float16 h0s[BM * PH0];  // 37888 B
  __shared__ __align__(16) _Float16 h1s[BM * PH1];  // 25600 B  -> 76800 total
  const int tid  = threadIdx.x;
  const int lane = tid & 63;
  const int wid  = tid >> 6;
  const int m0 = blockIdx.x * BM;

  // pad columns: 1.0 at the bias slot k==IN, 0 elsewhere in [IN, KP)
  for (int i = tid; i < BM * 22; i += 512) { int r = i / 22, c = IN0 + i - r * 22; xs [r * PX  + c] = (_Float16)(c == IN0 ? 1.f : 0.f); }
  for (int i = tid; i < BM * 19; i += 512) { int r = i / 19, c = H0  + i - r * 19; h0s[r * PH0 + c] = (_Float16)(c == H0  ? 1.f : 0.f); }
  for (int i = tid; i < BM * 13; i += 512) { int r = i / 13, c = H1  + i - r * 13; h1s[r * PH1 + c] = (_Float16)(c == H1  ? 1.f : 0.f); }

  // stage x (fp32 -> fp16) into LDS, float2 loads, packed b32 LDS writes
  for (int i = tid; i < BM * 37; i += 512) {
    int r = i / 37, p = i - r * 37;
    float2 v = ((const float2*)x)[(size_t)(m0 + r) * 37 + p];
    f16x2 hv = {(_Float16)v.x, (_Float16)v.y};
    *(f16x2*)(xs + r * PX + 2 * p) = hv;
  }
  __syncthreads();

  // L0: 17 tiles -> 16 @ S=4 (2/wave exact) + tile 16 as 2 half-units
  layer_part<KS0, H0, PX,  PH0, false, 4, 1>(xs, h0s, nullptr, wt0, lane, wid, 0, 16);
  layer_part<KS0, H0, PX,  PH0, false, 2, 2>(xs, h0s, nullptr, wt0, lane, wid, 16, 2);
  __syncthreads();
  // L1: 12 tiles -> 8 @ S=4 (1/wave) + tiles 8-11 as 8 half-units (1/wave)
  layer_part<KS1, H1, PH0, PH1, false, 4, 1>(h0s, h1s, nullptr, wt1, lane, wid, 0, 8);
  layer_part<KS1, H1, PH0, PH1, false, 2, 2>(h0s, h1s, nullptr, wt1, lane, wid, 8, 8);
  __syncthreads();
  // L2: 4 tiles -> 8 @ S=2, 1/wave exact
  layer_part<KS2, H2, PH1, 1,   true,  2, 2>(h1s, nullptr, out + (size_t)m0 * 64,
                                             wt2, lane, wid, 0, 8);
}

// Pack weights into fragment-major order, 3 matrices per layer.
// One thread per (chunk, lane): chunk c = (t*KS + ks)*3 + m, halfs j:
// k = ks*32+(lane>>4)*8+j, n = t*16+(lane&15).
// m=0: 2*log2e*mask*Wf1 (bias row 2*log2e*bf1); m=1: same for Wf2;
// m=2: log2e*(Wtb - Wta) (bias row log2e*(btb - bta)). Zero outside range.
__global__ void pack_w(const float* __restrict__ wf1, const float* __restrict__ wf2,
                       const float* __restrict__ wta, const float* __restrict__ wtb,
                       const float* __restrict__ bf1, const float* __restrict__ bf2,
                       const float* __restrict__ bta, const float* __restrict__ btb,
                       const int* __restrict__ mask, _Float16* __restrict__ wt,
                       int IN, int HID, int KS, int NT)
{
  const float SC2 = 2.885390081777927f;   // 2*log2(e)
  const float SC1 = 1.4426950408889634f;  // log2(e)
  int idx = blockIdx.x * 256 + threadIdx.x;
  int total = NT * KS * 3 * 64;
  if (idx >= total) return;
  int lane = idx & 63;
  int c = idx >> 6;          // chunk = (t*KS + ks)*3 + m
  int m = c % 3;
  int tk = c / 3;
  int ks = tk % KS;
  int t  = tk / KS;
  int n  = t * 16 + (lane & 15);
  int k0 = ks * 32 + (lane >> 4) * 8;
  f16x8 v = {};
  if (n < HID) {
    #pragma unroll
    for (int j = 0; j < 8; ++j) {
      int k = k0 + j;
      float f = 0.f;
      if (k < IN) {
        if (m == 0)      f = SC2 * wf1[k * HID + n] * (float)mask[k * HID + n];
        else if (m == 1) f = SC2 * wf2[k * HID + n] * (float)mask[k * HID + n];
        else             f = SC1 * (wtb[k * HID + n] - wta[k * HID + n]);
      } else if (k == IN) {
        if (m == 0)      f = SC2 * bf1[n];
        else if (m == 1) f = SC2 * bf2[n];
        else             f = SC1 * (btb[n] - bta[n]);
      }
      v[j] = (_Float16)f;
    }
  }
  *(f16x8*)(wt + (size_t)idx * 8) = v;
}

extern "C" void kernel_launch(void* const* d_in, const int* in_sizes, int n_in,
                              void* d_out, int out_size, void* d_ws, size_t ws_size,
                              hipStream_t stream)
{
  const float* x = (const float*)d_in[0];
  const float* Wf1_0 = (const float*)d_in[1];
  const float* bf1_0 = (const float*)d_in[2];
  const float* Wf2_0 = (const float*)d_in[3];
  const float* bf2_0 = (const float*)d_in[4];
  const float* Wta_0 = (const float*)d_in[5];
  const float* bta_0 = (const float*)d_in[6];
  const float* Wtb_0 = (const float*)d_in[7];
  const float* btb_0 = (const float*)d_in[8];
  const int*   msk_0 = (const int*)  d_in[9];
  const float* Wf1_1 = (const float*)d_in[10];
  const float* bf1_1 = (const float*)d_in[11];
  const float* Wf2_1 = (const float*)d_in[12];
  const float* bf2_1 = (const float*)d_in[13];
  const float* Wta_1 = (const float*)d_in[14];
  const float* bta_1 = (const float*)d_in[15];
  const float* Wtb_1 = (const float*)d_in[16];
  const float* btb_1 = (const float*)d_in[17];
  const int*   msk_1 = (const int*)  d_in[18];
  const float* Wf1_2 = (const float*)d_in[19];
  const float* bf1_2 = (const float*)d_in[20];
  const float* Wf2_2 = (const float*)d_in[21];
  const float* bf2_2 = (const float*)d_in[22];
  const float* Wta_2 = (const float*)d_in[23];
  const float* bta_2 = (const float*)d_in[24];
  const float* Wtb_2 = (const float*)d_in[25];
  const float* btb_2 = (const float*)d_in[26];
  const int*   msk_2 = (const int*)  d_in[27];

  char* ws = (char*)d_ws;
  _Float16* wt0 = (_Float16*)(ws + 0);        // 17*3*3*1024 = 156672
  _Float16* wt1 = (_Float16*)(ws + 156672);   // 12*9*3*1024 = 331776
  _Float16* wt2 = (_Float16*)(ws + 488448);   //  4*6*3*1024 =  73728

  pack_w<<<(17 * KS0 * 3 * 64 + 255) / 256, 256, 0, stream>>>(
      Wf1_0, Wf2_0, Wta_0, Wtb_0, bf1_0, bf2_0, bta_0, btb_0, msk_0, wt0, IN0, H0, KS0, 17);
  pack_w<<<(12 * KS1 * 3 * 64 + 255) / 256, 256, 0, stream>>>(
      Wf1_1, Wf2_1, Wta_1, Wtb_1, bf1_1, bf2_1, bta_1, btb_1, msk_1, wt1, H0, H1, KS1, 12);
  pack_w<<<( 4 * KS2 * 3 * 64 + 255) / 256, 256, 0, stream>>>(
      Wf1_2, Wf2_2, Wta_2, Wtb_2, bf1_2, bf2_2, bta_2, btb_2, msk_2, wt2, H1, H2, KS2, 4);

  cfc_fused<<<65536 / BM, 512, 0, stream>>>(x, wt0, wt1, wt2, (float*)d_out);
}

// Round 17
// 69.610 us; speedup vs baseline: 1.1547x; 1.1547x over previous
//
#include <hip/hip_runtime.h>
#include <hip/hip_fp16.h>

typedef _Float16 f16x8 __attribute__((ext_vector_type(8)));
typedef _Float16 f16x4 __attribute__((ext_vector_type(4)));
typedef _Float16 f16x2 __attribute__((ext_vector_type(2)));
typedef float    f32x4 __attribute__((ext_vector_type(4)));

#define BM 64     // 64-row block tile -> 76.8 KB LDS -> 2 blocks/CU, 4 waves/SIMD

// layer geometry (h=0 => only first IN rows of each weight matter; the
// padded K range includes a bias row at k==IN carrying 1.0 in activations)
#define IN0 74
#define H0  269
#define H1  179
#define H2  64
#define KS0 3     // ceil((IN0+1)/32)
#define KS1 9     // ceil((H0+1)/32)
#define KS2 6     // ceil((H1+1)/32)
#define NP0 272
#define NP1 192
#define NP2 64
#define PX  104   // LDS row pitches (halfs)
#define PH0 296
#define PH1 200

// SWAPPED operands: weights as the A-matrix, activations as B.
// C/D layout: col(lane&15)=batch row, row(lg*4+q)=feature -> each lane's 4
// outputs are 4 CONSECUTIVE features of one batch row.
#define MFMA16(a, b, c) __builtin_amdgcn_mfma_f32_16x16x32_f16(a, b, c, 0, 0, 0)

// THREE matrices per layer: m0 = 2*log2e*mask*Wf1 (+bias row), m1 = same for
// Wf2, m2 = log2e*(Wtb-Wta) (+bias). log2e folded at pack time; rform2 uses
// the RAW v_exp_f32 instruction (__builtin_amdgcn_exp2f), NOT libm exp2f —
// r15/r16 showed libm exp2 costs ~+9us of VALU vs the native path.
// tanh(f) = 1-2r, r = 1/(1+exp2(acc)); ti = sigmoid(tb-ta) = 1/(1+exp2(-acc2)).
__device__ __forceinline__ float rform2(float y) {
  return __builtin_amdgcn_rcpf(1.f + __builtin_amdgcn_exp2f(y));
}

// One PART of a CfC layer: NU work-units starting at tile T0, each unit
// u -> (tile T0 + u/G, row-group u%G of S*16 rows). 8 waves stride the
// units. Layers are split into a large-S part + small-S remainder so
// per-wave cost is uniform (r12's ceil() tails).
// Per unit ONE K-sweep, 3 matrices accumulating (acc[3][S] AGPRs), rolling
// 1-ahead B window in a FORCIBLY ROLLED (#pragma unroll 1) ks loop, A-reads
// just-in-time in the unrolled s-loop (r12 structure, the proven best).
template<int KS, int HID, int IPITCH, int OPITCH, bool LAST, int S, int G>
__device__ __forceinline__ void layer_part(
    const _Float16* in_lds, _Float16* out_lds, float* out_g,
    const _Float16* __restrict__ wt, int lane, int wid, int T0, int NU)
{
  const int l15 = lane & 15;
  const int lg  = lane >> 4;
  #pragma unroll 1
  for (int u = wid; u < NU; u += 8) {
    const int t     = T0 + u / G;
    const int mbase = (u % G) * (S * 16);
    const _Float16* a_base = in_lds + (mbase + l15) * IPITCH + lg * 8;
    const _Float16* wtt = wt + (size_t)(t * KS * 3) * 512 + lane * 8;

    f32x4 acc[3][S] = {};
    f16x8 b0 = *(const f16x8*)(wtt);
    f16x8 b1 = *(const f16x8*)(wtt + 512);
    f16x8 b2 = *(const f16x8*)(wtt + 1024);
    #pragma unroll 1
    for (int ks = 0; ks < KS - 1; ++ks) {
      const _Float16* wn = wtt + (size_t)(ks + 1) * 1536;
      f16x8 n0 = *(const f16x8*)(wn);
      f16x8 n1 = *(const f16x8*)(wn + 512);
      f16x8 n2 = *(const f16x8*)(wn + 1024);
      #pragma unroll
      for (int s = 0; s < S; ++s) {
        f16x8 a = *(const f16x8*)(a_base + s * 16 * IPITCH + ks * 32);
        acc[0][s] = MFMA16(b0, a, acc[0][s]);
        acc[1][s] = MFMA16(b1, a, acc[1][s]);
        acc[2][s] = MFMA16(b2, a, acc[2][s]);
      }
      b0 = n0; b1 = n1; b2 = n2;
    }
    #pragma unroll
    for (int s = 0; s < S; ++s) {
      f16x8 a = *(const f16x8*)(a_base + s * 16 * IPITCH + (KS - 1) * 32);
      acc[0][s] = MFMA16(b0, a, acc[0][s]);
      acc[1][s] = MFMA16(b1, a, acc[1][s]);
      acc[2][s] = MFMA16(b2, a, acc[2][s]);
    }

    // epilogue: per s, this lane owns batch row m and 4 consecutive features
    const int nb = t * 16 + lg * 4;
    #pragma unroll
    for (int s = 0; s < S; ++s) {
      const int m = mbase + s * 16 + l15;
      float o[4];
      #pragma unroll
      for (int q = 0; q < 4; ++q) {
        float r1 = rform2(acc[0][s][q]);        // acc0 = 2*log2e*f1
        float r2 = rform2(acc[1][s][q]);        // acc1 = 2*log2e*f2
        float ti = rform2(-acc[2][s][q]);       // sigmoid(tb-ta)
        o[q] = 1.f - 2.f * (r1 - ti * (r1 - r2));
      }
      if (LAST) {
        float4 v = make_float4(o[0], o[1], o[2], o[3]);
        *(float4*)(out_g + m * 64 + nb) = v;       // NP2==H2, no guard
      } else if (nb + 4 <= HID) {
        f16x4 h = {(_Float16)o[0], (_Float16)o[1], (_Float16)o[2], (_Float16)o[3]};
        *(f16x4*)(out_lds + m * OPITCH + nb) = h;  // one b64 write
      } else {
        #pragma unroll
        for (int q = 0; q < 4; ++q)
          if (nb + q < HID) out_lds[m * OPITCH + nb + q] = (_Float16)o[q];
      }
    }
  }
}

__global__ __launch_bounds__(512, 4) void cfc_fused(
    const float* __restrict__ x,
    const _Float16* __restrict__ wt0, const _Float16* __restrict__ wt1,
    const _Float16* __restrict__ wt2,
    float* __restrict__ out)
{
  __shared__ __align__(16) _Float16 xs [BM * PX];   // 13312 B
  __shared__ __align__(16) _Float16 h0s[BM * PH0];  // 37888 B
  __shared__ __align__(16) _Float16 h1s[BM * PH1];  // 25600 B  -> 76800 total
  const int tid  = threadIdx.x;
  const int lane = tid & 63;
  const int wid  = tid >> 6;
  const int m0 = blockIdx.x * BM;

  // pad columns: 1.0 at the bias slot k==IN, 0 elsewhere in [IN, KP)
  for (int i = tid; i < BM * 22; i += 512) { int r = i / 22, c = IN0 + i - r * 22; xs [r * PX  + c] = (_Float16)(c == IN0 ? 1.f : 0.f); }
  for (int i = tid; i < BM * 19; i += 512) { int r = i / 19, c = H0  + i - r * 19; h0s[r * PH0 + c] = (_Float16)(c == H0  ? 1.f : 0.f); }
  for (int i = tid; i < BM * 13; i += 512) { int r = i / 13, c = H1  + i - r * 13; h1s[r * PH1 + c] = (_Float16)(c == H1  ? 1.f : 0.f); }

  // stage x (fp32 -> fp16) into LDS, float2 loads, packed b32 LDS writes
  for (int i = tid; i < BM * 37; i += 512) {
    int r = i / 37, p = i - r * 37;
    float2 v = ((const float2*)x)[(size_t)(m0 + r) * 37 + p];
    f16x2 hv = {(_Float16)v.x, (_Float16)v.y};
    *(f16x2*)(xs + r * PX + 2 * p) = hv;
  }
  __syncthreads();

  // L0: 17 tiles -> 16 @ S=4 (2/wave exact) + tile 16 as 2 half-units
  layer_part<KS0, H0, PX,  PH0, false, 4, 1>(xs, h0s, nullptr, wt0, lane, wid, 0, 16);
  layer_part<KS0, H0, PX,  PH0, false, 2, 2>(xs, h0s, nullptr, wt0, lane, wid, 16, 2);
  __syncthreads();
  // L1: 12 tiles -> 8 @ S=4 (1/wave) + tiles 8-11 as 8 half-units (1/wave)
  layer_part<KS1, H1, PH0, PH1, false, 4, 1>(h0s, h1s, nullptr, wt1, lane, wid, 0, 8);
  layer_part<KS1, H1, PH0, PH1, false, 2, 2>(h0s, h1s, nullptr, wt1, lane, wid, 8, 8);
  __syncthreads();
  // L2: 4 tiles -> 8 @ S=2, 1/wave exact
  layer_part<KS2, H2, PH1, 1,   true,  2, 2>(h1s, nullptr, out + (size_t)m0 * 64,
                                             wt2, lane, wid, 0, 8);
}

// Pack weights into fragment-major order, 3 matrices per layer.
// One thread per (chunk, lane): chunk c = (t*KS + ks)*3 + m, halfs j:
// k = ks*32+(lane>>4)*8+j, n = t*16+(lane&15).
// m=0: 2*log2e*mask*Wf1 (bias row 2*log2e*bf1); m=1: same for Wf2;
// m=2: log2e*(Wtb - Wta) (bias row log2e*(btb - bta)). Zero outside range.
__global__ void pack_w(const float* __restrict__ wf1, const float* __restrict__ wf2,
                       const float* __restrict__ wta, const float* __restrict__ wtb,
                       const float* __restrict__ bf1, const float* __restrict__ bf2,
                       const float* __restrict__ bta, const float* __restrict__ btb,
                       const int* __restrict__ mask, _Float16* __restrict__ wt,
                       int IN, int HID, int KS, int NT)
{
  const float SC2 = 2.885390081777927f;   // 2*log2(e)
  const float SC1 = 1.4426950408889634f;  // log2(e)
  int idx = blockIdx.x * 256 + threadIdx.x;
  int total = NT * KS * 3 * 64;
  if (idx >= total) return;
  int lane = idx & 63;
  int c = idx >> 6;          // chunk = (t*KS + ks)*3 + m
  int m = c % 3;
  int tk = c / 3;
  int ks = tk % KS;
  int t  = tk / KS;
  int n  = t * 16 + (lane & 15);
  int k0 = ks * 32 + (lane >> 4) * 8;
  f16x8 v = {};
  if (n < HID) {
    #pragma unroll
    for (int j = 0; j < 8; ++j) {
      int k = k0 + j;
      float f = 0.f;
      if (k < IN) {
        if (m == 0)      f = SC2 * wf1[k * HID + n] * (float)mask[k * HID + n];
        else if (m == 1) f = SC2 * wf2[k * HID + n] * (float)mask[k * HID + n];
        else             f = SC1 * (wtb[k * HID + n] - wta[k * HID + n]);
      } else if (k == IN) {
        if (m == 0)      f = SC2 * bf1[n];
        else if (m == 1) f = SC2 * bf2[n];
        else             f = SC1 * (btb[n] - bta[n]);
      }
      v[j] = (_Float16)f;
    }
  }
  *(f16x8*)(wt + (size_t)idx * 8) = v;
}

extern "C" void kernel_launch(void* const* d_in, const int* in_sizes, int n_in,
                              void* d_out, int out_size, void* d_ws, size_t ws_size,
                              hipStream_t stream)
{
  const float* x = (const float*)d_in[0];
  const float* Wf1_0 = (const float*)d_in[1];
  const float* bf1_0 = (const float*)d_in[2];
  const float* Wf2_0 = (const float*)d_in[3];
  const float* bf2_0 = (const float*)d_in[4];
  const float* Wta_0 = (const float*)d_in[5];
  const float* bta_0 = (const float*)d_in[6];
  const float* Wtb_0 = (const float*)d_in[7];
  const float* btb_0 = (const float*)d_in[8];
  const int*   msk_0 = (const int*)  d_in[9];
  const float* Wf1_1 = (const float*)d_in[10];
  const float* bf1_1 = (const float*)d_in[11];
  const float* Wf2_1 = (const float*)d_in[12];
  const float* bf2_1 = (const float*)d_in[13];
  const float* Wta_1 = (const float*)d_in[14];
  const float* bta_1 = (const float*)d_in[15];
  const float* Wtb_1 = (const float*)d_in[16];
  const float* btb_1 = (const float*)d_in[17];
  const int*   msk_1 = (const int*)  d_in[18];
  const float* Wf1_2 = (const float*)d_in[19];
  const float* bf1_2 = (const float*)d_in[20];
  const float* Wf2_2 = (const float*)d_in[21];
  const float* bf2_2 = (const float*)d_in[22];
  const float* Wta_2 = (const float*)d_in[23];
  const float* bta_2 = (const float*)d_in[24];
  const float* Wtb_2 = (const float*)d_in[25];
  const float* btb_2 = (const float*)d_in[26];
  const int*   msk_2 = (const int*)  d_in[27];

  char* ws = (char*)d_ws;
  _Float16* wt0 = (_Float16*)(ws + 0);        // 17*3*3*1024 = 156672
  _Float16* wt1 = (_Float16*)(ws + 156672);   // 12*9*3*1024 = 331776
  _Float16* wt2 = (_Float16*)(ws + 488448);   //  4*6*3*1024 =  73728

  pack_w<<<(17 * KS0 * 3 * 64 + 255) / 256, 256, 0, stream>>>(
      Wf1_0, Wf2_0, Wta_0, Wtb_0, bf1_0, bf2_0, bta_0, btb_0, msk_0, wt0, IN0, H0, KS0, 17);
  pack_w<<<(12 * KS1 * 3 * 64 + 255) / 256, 256, 0, stream>>>(
      Wf1_1, Wf2_1, Wta_1, Wtb_1, bf1_1, bf2_1, bta_1, btb_1, msk_1, wt1, H0, H1, KS1, 12);
  pack_w<<<( 4 * KS2 * 3 * 64 + 255) / 256, 256, 0, stream>>>(
      Wf1_2, Wf2_2, Wta_2, Wtb_2, bf1_2, bf2_2, bta_2, btb_2, msk_2, wt2, H1, H2, KS2, 4);

  cfc_fused<<<65536 / BM, 512, 0, stream>>>(x, wt0, wt1, wt2, (float*)d_out);
}

// Round 18
// 58.053 us; speedup vs baseline: 1.3845x; 1.1991x over previous
//
#include <hip/hip_runtime.h>
#include <hip/hip_fp16.h>

typedef _Float16 f16x8 __attribute__((ext_vector_type(8)));
typedef _Float16 f16x4 __attribute__((ext_vector_type(4)));
typedef _Float16 f16x2 __attribute__((ext_vector_type(2)));
typedef float    f32x4 __attribute__((ext_vector_type(4)));

#define BM 64     // 64-row block tile -> 76.8 KB LDS -> 2 blocks/CU, 4 waves/SIMD

// layer geometry (h=0 => only first IN rows of each weight matter; the
// padded K range includes a bias row at k==IN carrying 1.0 in activations)
#define IN0 74
#define H0  269
#define H1  179
#define H2  64
#define KS0 3     // ceil((IN0+1)/32)
#define KS1 9     // ceil((H0+1)/32)
#define KS2 6     // ceil((H1+1)/32)
#define NP0 272
#define NP1 192
#define NP2 64
#define PX  104   // LDS row pitches (halfs)
#define PH0 296
#define PH1 200

// pack work partition (threads per layer): NT*KS*3*64
#define PK0 9792
#define PK1 20736
#define PK2 4608
#define PKT (PK0 + PK1 + PK2)   // 35136

// SWAPPED operands: weights as the A-matrix, activations as B.
// C/D layout: col(lane&15)=batch row, row(lg*4+q)=feature -> each lane's 4
// outputs are 4 CONSECUTIVE features of one batch row.
#define MFMA16(a, b, c) __builtin_amdgcn_mfma_f32_16x16x32_f16(a, b, c, 0, 0, 0)

// THREE matrices per layer: m0 = 2*log2e*mask*Wf1 (+bias row), m1 = same for
// Wf2, m2 = log2e*(Wtb-Wta) (+bias). log2e folded at pack time; rform2 uses
// the RAW v_exp_f32 instruction (__builtin_amdgcn_exp2f), NOT libm exp2f —
// r15/r16 showed libm exp2 costs ~+9us of VALU vs the native path.
// tanh(f) = 1-2r, r = 1/(1+exp2(acc)); ti = sigmoid(tb-ta) = 1/(1+exp2(-acc2)).
__device__ __forceinline__ float rform2(float y) {
  return __builtin_amdgcn_rcpf(1.f + __builtin_amdgcn_exp2f(y));
}

// One PART of a CfC layer: NU work-units starting at tile T0, each unit
// u -> (tile T0 + u/G, row-group u%G of S*16 rows). 8 waves stride the
// units. Layers are split into a large-S part + small-S remainder so
// per-wave cost is uniform.
// Per unit ONE K-sweep, 3 matrices accumulating (acc[3][S] AGPRs), rolling
// 1-ahead B window in a FORCIBLY ROLLED (#pragma unroll 1) ks loop, A-reads
// just-in-time in the unrolled s-loop (r12/r17 structure, the proven best).
template<int KS, int HID, int IPITCH, int OPITCH, bool LAST, int S, int G>
__device__ __forceinline__ void layer_part(
    const _Float16* in_lds, _Float16* out_lds, float* out_g,
    const _Float16* __restrict__ wt, int lane, int wid, int T0, int NU)
{
  const int l15 = lane & 15;
  const int lg  = lane >> 4;
  #pragma unroll 1
  for (int u = wid; u < NU; u += 8) {
    const int t     = T0 + u / G;
    const int mbase = (u % G) * (S * 16);
    const _Float16* a_base = in_lds + (mbase + l15) * IPITCH + lg * 8;
    const _Float16* wtt = wt + (size_t)(t * KS * 3) * 512 + lane * 8;

    f32x4 acc[3][S] = {};
    f16x8 b0 = *(const f16x8*)(wtt);
    f16x8 b1 = *(const f16x8*)(wtt + 512);
    f16x8 b2 = *(const f16x8*)(wtt + 1024);
    #pragma unroll 1
    for (int ks = 0; ks < KS - 1; ++ks) {
      const _Float16* wn = wtt + (size_t)(ks + 1) * 1536;
      f16x8 n0 = *(const f16x8*)(wn);
      f16x8 n1 = *(const f16x8*)(wn + 512);
      f16x8 n2 = *(const f16x8*)(wn + 1024);
      #pragma unroll
      for (int s = 0; s < S; ++s) {
        f16x8 a = *(const f16x8*)(a_base + s * 16 * IPITCH + ks * 32);
        acc[0][s] = MFMA16(b0, a, acc[0][s]);
        acc[1][s] = MFMA16(b1, a, acc[1][s]);
        acc[2][s] = MFMA16(b2, a, acc[2][s]);
      }
      b0 = n0; b1 = n1; b2 = n2;
    }
    #pragma unroll
    for (int s = 0; s < S; ++s) {
      f16x8 a = *(const f16x8*)(a_base + s * 16 * IPITCH + (KS - 1) * 32);
      acc[0][s] = MFMA16(b0, a, acc[0][s]);
      acc[1][s] = MFMA16(b1, a, acc[1][s]);
      acc[2][s] = MFMA16(b2, a, acc[2][s]);
    }

    // epilogue: per s, this lane owns batch row m and 4 consecutive features
    const int nb = t * 16 + lg * 4;
    #pragma unroll
    for (int s = 0; s < S; ++s) {
      const int m = mbase + s * 16 + l15;
      float o[4];
      #pragma unroll
      for (int q = 0; q < 4; ++q) {
        float r1 = rform2(acc[0][s][q]);        // acc0 = 2*log2e*f1
        float r2 = rform2(acc[1][s][q]);        // acc1 = 2*log2e*f2
        float ti = rform2(-acc[2][s][q]);       // sigmoid(tb-ta)
        o[q] = 1.f - 2.f * (r1 - ti * (r1 - r2));
      }
      if (LAST) {
        float4 v = make_float4(o[0], o[1], o[2], o[3]);
        *(float4*)(out_g + m * 64 + nb) = v;       // NP2==H2, no guard
      } else if (nb + 4 <= HID) {
        f16x4 h = {(_Float16)o[0], (_Float16)o[1], (_Float16)o[2], (_Float16)o[3]};
        *(f16x4*)(out_lds + m * OPITCH + nb) = h;  // one b64 write
      } else {
        #pragma unroll
        for (int q = 0; q < 4; ++q)
          if (nb + q < HID) out_lds[m * OPITCH + nb + q] = (_Float16)o[q];
      }
    }
  }
}

__global__ __launch_bounds__(512, 4) void cfc_fused(
    const float* __restrict__ x,
    const _Float16* __restrict__ wt0, const _Float16* __restrict__ wt1,
    const _Float16* __restrict__ wt2,
    float* __restrict__ out)
{
  __shared__ __align__(16) _Float16 xs [BM * PX];   // 13312 B
  __shared__ __align__(16) _Float16 h0s[BM * PH0];  // 37888 B
  __shared__ __align__(16) _Float16 h1s[BM * PH1];  // 25600 B  -> 76800 total
  const int tid  = threadIdx.x;
  const int lane = tid & 63;
  const int wid  = tid >> 6;
  const int m0 = blockIdx.x * BM;

  // pad columns: 1.0 at the bias slot k==IN, 0 elsewhere in [IN, KP)
  for (int i = tid; i < BM * 22; i += 512) { int r = i / 22, c = IN0 + i - r * 22; xs [r * PX  + c] = (_Float16)(c == IN0 ? 1.f : 0.f); }
  for (int i = tid; i < BM * 19; i += 512) { int r = i / 19, c = H0  + i - r * 19; h0s[r * PH0 + c] = (_Float16)(c == H0  ? 1.f : 0.f); }
  for (int i = tid; i < BM * 13; i += 512) { int r = i / 13, c = H1  + i - r * 13; h1s[r * PH1 + c] = (_Float16)(c == H1  ? 1.f : 0.f); }

  // stage x (fp32 -> fp16) into LDS, float2 loads, packed b32 LDS writes
  for (int i = tid; i < BM * 37; i += 512) {
    int r = i / 37, p = i - r * 37;
    float2 v = ((const float2*)x)[(size_t)(m0 + r) * 37 + p];
    f16x2 hv = {(_Float16)v.x, (_Float16)v.y};
    *(f16x2*)(xs + r * PX + 2 * p) = hv;
  }
  __syncthreads();

  // L0: 17 tiles -> 16 @ S=4 (2/wave exact) + tile 16 as 2 half-units
  layer_part<KS0, H0, PX,  PH0, false, 4, 1>(xs, h0s, nullptr, wt0, lane, wid, 0, 16);
  layer_part<KS0, H0, PX,  PH0, false, 2, 2>(xs, h0s, nullptr, wt0, lane, wid, 16, 2);
  __syncthreads();
  // L1: 12 tiles -> 8 @ S=4 (1/wave) + tiles 8-11 as 8 half-units (1/wave)
  layer_part<KS1, H1, PH0, PH1, false, 4, 1>(h0s, h1s, nullptr, wt1, lane, wid, 0, 8);
  layer_part<KS1, H1, PH0, PH1, false, 2, 2>(h0s, h1s, nullptr, wt1, lane, wid, 8, 8);
  __syncthreads();
  // L2: 4 tiles -> 8 @ S=2, 1/wave exact
  layer_part<KS2, H2, PH1, 1,   true,  2, 2>(h1s, nullptr, out + (size_t)m0 * 64,
                                             wt2, lane, wid, 0, 8);
}

// Pack one element-group of one layer into fragment-major order.
// idx -> chunk c = (t*KS + ks)*3 + m, lane; halfs j:
// k = ks*32+(lane>>4)*8+j, n = t*16+(lane&15).
// m=0: 2*log2e*mask*Wf1 (bias row 2*log2e*bf1); m=1: same for Wf2;
// m=2: log2e*(Wtb - Wta) (bias row log2e*(btb - bta)). Zero outside range.
__device__ __forceinline__ void pack_one(
    int idx, const float* wf1, const float* wf2,
    const float* wta, const float* wtb,
    const float* bf1, const float* bf2,
    const float* bta, const float* btb,
    const int* mask, _Float16* wt, int IN, int HID, int KS)
{
  const float SC2 = 2.885390081777927f;   // 2*log2(e)
  const float SC1 = 1.4426950408889634f;  // log2(e)
  int lane = idx & 63;
  int c = idx >> 6;
  int m = c % 3;
  int tk = c / 3;
  int ks = tk % KS;
  int t  = tk / KS;
  int n  = t * 16 + (lane & 15);
  int k0 = ks * 32 + (lane >> 4) * 8;
  f16x8 v = {};
  if (n < HID) {
    #pragma unroll
    for (int j = 0; j < 8; ++j) {
      int k = k0 + j;
      float f = 0.f;
      if (k < IN) {
        if (m == 0)      f = SC2 * wf1[k * HID + n] * (float)mask[k * HID + n];
        else if (m == 1) f = SC2 * wf2[k * HID + n] * (float)mask[k * HID + n];
        else             f = SC1 * (wtb[k * HID + n] - wta[k * HID + n]);
      } else if (k == IN) {
        if (m == 0)      f = SC2 * bf1[n];
        else if (m == 1) f = SC2 * bf2[n];
        else             f = SC1 * (btb[n] - bta[n]);
      }
      v[j] = (_Float16)f;
    }
  }
  *(f16x8*)(wt + (size_t)idx * 8) = v;
}

// ALL three layers packed in ONE launch (idx-range partitioned) — the three
// separate pack_w launches cost ~13us of graph-serialized launch overhead
// vs the ~56us main kernel.
__global__ void pack_all(
    const float* wf1_0, const float* wf2_0, const float* wta_0, const float* wtb_0,
    const float* bf1_0, const float* bf2_0, const float* bta_0, const float* btb_0,
    const int* msk_0,
    const float* wf1_1, const float* wf2_1, const float* wta_1, const float* wtb_1,
    const float* bf1_1, const float* bf2_1, const float* bta_1, const float* btb_1,
    const int* msk_1,
    const float* wf1_2, const float* wf2_2, const float* wta_2, const float* wtb_2,
    const float* bf1_2, const float* bf2_2, const float* bta_2, const float* btb_2,
    const int* msk_2,
    _Float16* wt0, _Float16* wt1, _Float16* wt2)
{
  int idx = blockIdx.x * 256 + threadIdx.x;
  if (idx < PK0) {
    pack_one(idx, wf1_0, wf2_0, wta_0, wtb_0, bf1_0, bf2_0, bta_0, btb_0,
             msk_0, wt0, IN0, H0, KS0);
  } else if (idx < PK0 + PK1) {
    pack_one(idx - PK0, wf1_1, wf2_1, wta_1, wtb_1, bf1_1, bf2_1, bta_1, btb_1,
             msk_1, wt1, H0, H1, KS1);
  } else if (idx < PKT) {
    pack_one(idx - PK0 - PK1, wf1_2, wf2_2, wta_2, wtb_2, bf1_2, bf2_2, bta_2, btb_2,
             msk_2, wt2, H1, H2, KS2);
  }
}

extern "C" void kernel_launch(void* const* d_in, const int* in_sizes, int n_in,
                              void* d_out, int out_size, void* d_ws, size_t ws_size,
                              hipStream_t stream)
{
  const float* x = (const float*)d_in[0];
  const float* Wf1_0 = (const float*)d_in[1];
  const float* bf1_0 = (const float*)d_in[2];
  const float* Wf2_0 = (const float*)d_in[3];
  const float* bf2_0 = (const float*)d_in[4];
  const float* Wta_0 = (const float*)d_in[5];
  const float* bta_0 = (const float*)d_in[6];
  const float* Wtb_0 = (const float*)d_in[7];
  const float* btb_0 = (const float*)d_in[8];
  const int*   msk_0 = (const int*)  d_in[9];
  const float* Wf1_1 = (const float*)d_in[10];
  const float* bf1_1 = (const float*)d_in[11];
  const float* Wf2_1 = (const float*)d_in[12];
  const float* bf2_1 = (const float*)d_in[13];
  const float* Wta_1 = (const float*)d_in[14];
  const float* bta_1 = (const float*)d_in[15];
  const float* Wtb_1 = (const float*)d_in[16];
  const float* btb_1 = (const float*)d_in[17];
  const int*   msk_1 = (const int*)  d_in[18];
  const float* Wf1_2 = (const float*)d_in[19];
  const float* bf1_2 = (const float*)d_in[20];
  const float* Wf2_2 = (const float*)d_in[21];
  const float* bf2_2 = (const float*)d_in[22];
  const float* Wta_2 = (const float*)d_in[23];
  const float* bta_2 = (const float*)d_in[24];
  const float* Wtb_2 = (const float*)d_in[25];
  const float* btb_2 = (const float*)d_in[26];
  const int*   msk_2 = (const int*)  d_in[27];

  char* ws = (char*)d_ws;
  _Float16* wt0 = (_Float16*)(ws + 0);        // 17*3*3*1024 = 156672
  _Float16* wt1 = (_Float16*)(ws + 156672);   // 12*9*3*1024 = 331776
  _Float16* wt2 = (_Float16*)(ws + 488448);   //  4*6*3*1024 =  73728

  pack_all<<<(PKT + 255) / 256, 256, 0, stream>>>(
      Wf1_0, Wf2_0, Wta_0, Wtb_0, bf1_0, bf2_0, bta_0, btb_0, msk_0,
      Wf1_1, Wf2_1, Wta_1, Wtb_1, bf1_1, bf2_1, bta_1, btb_1, msk_1,
      Wf1_2, Wf2_2, Wta_2, Wtb_2, bf1_2, bf2_2, bta_2, btb_2, msk_2,
      wt0, wt1, wt2);

  cfc_fused<<<65536 / BM, 512, 0, stream>>>(x, wt0, wt1, wt2, (float*)d_out);
}